// Round 1
// baseline (479.579 us; speedup 1.0000x reference)
//
#include <hip/hip_runtime.h>

typedef unsigned short u16;
typedef float f32x4 __attribute__((ext_vector_type(4)));
typedef float f32x8 __attribute__((ext_vector_type(8)));
typedef u16   u16x4 __attribute__((ext_vector_type(4)));
typedef u16   u16x8 __attribute__((ext_vector_type(8)));
typedef __bf16 bf16x8 __attribute__((ext_vector_type(8)));

// ---------------- workspace layout (bytes) ----------------
// peak ~110.5 MB; x_bf region is reused for out_bf/rh_bf after G1.
#define WS_W       0u            // w softmax [12*3] f32
#define WS_ACC     256u          // 5 accumulators x 12 f32 (240B)
#define WS_BIASRH  512u          // [12*512] f32 = 24576B
#define WS_WPB     25600u        // Wp bf16 [512*1024]
#define WS_PHWB    1074176u      // phW bf16 [1024*512]
#define WS_RW1B    2122752u      // rW1[:, :512] bf16 [512*512]
#define WS_W1B     2647040u      // opW1 bf16 [36*512*512]
#define WS_W2B     21521408u     // opW2 bf16 [36*512*512]
#define WS_XPB     40395776u     // xp bf16 [12288*512]
#define WS_H1B     52978688u     // h1 bf16 [36*1024*512]
#define WS_XBF     90727424u     // x bf16 [12288*1024]   (dead after G1)
#define WS_OUTB    90727424u     // out bf16 [12288*512]  (aliases XBF lo)
#define WS_RHB     103310336u    // rh bf16 [12288*512]   (aliases XBF hi)

#define OUT_LG   6291456
#define OUT_PRED 6451200
#define OUT_DEC  19034112

__device__ __forceinline__ u16 f2bf(float f) {
    unsigned u = __builtin_bit_cast(unsigned, f);
    return (u16)((u + 0x7FFFu + ((u >> 16) & 1u)) >> 16);
}
__device__ __forceinline__ float bf2f(u16 h) {
    return __builtin_bit_cast(float, (unsigned)h << 16);
}

typedef __attribute__((address_space(1))) void* gas1p;
typedef __attribute__((address_space(3))) void* las3p;
__device__ __forceinline__ void gload16(const u16* g, u16* l) {
    __builtin_amdgcn_global_load_lds((gas1p)(unsigned long long)g,
                                     (las3p)(unsigned)(unsigned long long)l,
                                     16, 0, 0);
}

__device__ __forceinline__ void zero_acc(f32x4 (&a)[4][4]) {
#pragma unroll
    for (int i = 0; i < 4; i++)
#pragma unroll
        for (int j = 0; j < 4; j++)
            a[i][j] = (f32x4){0.f, 0.f, 0.f, 0.f};
}

// 128x128 tile, BK=32, 4 waves, each wave 64x64 via 4x4 mfma_16x16x32_bf16.
// Computes C = A * B^T : A rows pitch pa, B rows pitch pb (both bf16 [*, K]).
__device__ __forceinline__ void mfma_loop(
    const u16* __restrict__ Ab, size_t pa,
    const u16* __restrict__ Bb, size_t pb,
    int K, u16* sA, u16* sB, f32x4 (&acc)[4][4])
{
    const int tid = threadIdx.x;
    const int l = tid & 63, wv = tid >> 6;
    const int wm = (wv >> 1) * 64, wn = (wv & 1) * 64;
    const int m16 = l & 15, k8 = l >> 4;
    const int kc = (tid & 3) * 8;
    const size_t ra0 = (size_t)(tid >> 2) * pa + kc;
    const size_t ra1 = ra0 + 64 * pa;
    const size_t rb0 = (size_t)(tid >> 2) * pb + kc;
    const size_t rb1 = rb0 + 64 * pb;
    u16* dA0 = sA + tid * 8;          u16* dA1 = sA + (tid + 256) * 8;
    u16* dB0 = sB + tid * 8;          u16* dB1 = sB + (tid + 256) * 8;
    const int aO = (wm + m16) * 32 + k8 * 8;
    const int bO = (wn + m16) * 32 + k8 * 8;
    for (int kt = 0; kt < K; kt += 32) {
        __syncthreads();
        gload16(Ab + ra0 + kt, dA0);
        gload16(Ab + ra1 + kt, dA1);
        gload16(Bb + rb0 + kt, dB0);
        gload16(Bb + rb1 + kt, dB1);
        __syncthreads();
        bf16x8 af[4], bv[4];
#pragma unroll
        for (int i = 0; i < 4; i++) af[i] = *(const bf16x8*)(sA + aO + i * 512);
#pragma unroll
        for (int i = 0; i < 4; i++) bv[i] = *(const bf16x8*)(sB + bO + i * 512);
#pragma unroll
        for (int i = 0; i < 4; i++)
#pragma unroll
            for (int j = 0; j < 4; j++)
                acc[i][j] = __builtin_amdgcn_mfma_f32_16x16x32_bf16(af[i], bv[j], acc[i][j], 0, 0, 0);
    }
}

// ---------------- conversion + softmax(w) ----------------
__global__ __launch_bounds__(256) void cvt6(
    const float* __restrict__ x,    u16* __restrict__ xbf,
    const float* __restrict__ opW1, u16* __restrict__ w1b,
    const float* __restrict__ opW2, u16* __restrict__ w2b,
    const float* __restrict__ Wp,   u16* __restrict__ wpb,
    const float* __restrict__ phW,  u16* __restrict__ phwb,
    const float* __restrict__ rW1,  u16* __restrict__ rw1b,
    const float* __restrict__ op_logits, float* __restrict__ wbuf)
{
    if (blockIdx.x == 0 && threadIdx.x < 12) {
        const int t = threadIdx.x;
        float l0 = op_logits[t*3+0], l1 = op_logits[t*3+1], l2 = op_logits[t*3+2];
        float mx = fmaxf(l0, fmaxf(l1, l2));
        float e0 = expf(l0-mx), e1 = expf(l1-mx), e2 = expf(l2-mx);
        float inv = 1.f / (e0 + e1 + e2);
        wbuf[t*3+0] = e0*inv; wbuf[t*3+1] = e1*inv; wbuf[t*3+2] = e2*inv;
    }
    int i = (blockIdx.x * 256 + threadIdx.x) * 4;
    const float* s; u16* d;
    if (i < 12582912)                 { s = x;    d = xbf;  }
    else if ((i -= 12582912) < 9437184) { s = opW1; d = w1b; }
    else if ((i -= 9437184)  < 9437184) { s = opW2; d = w2b; }
    else if ((i -= 9437184)  < 524288)  { s = Wp;   d = wpb; }
    else if ((i -= 524288)   < 524288)  { s = phW;  d = phwb; }
    else {
        i -= 524288;  // [0, 262144): rW1 cols 0..511 of 519
        int row = i >> 9, j = i & 511;
        const float* sr = rW1 + (size_t)row * 519 + j;
        u16x4 o = { f2bf(sr[0]), f2bf(sr[1]), f2bf(sr[2]), f2bf(sr[3]) };
        *(u16x4*)(rw1b + i) = o;
        return;
    }
    f32x4 v = *(const f32x4*)(s + i);
    u16x4 o = { f2bf(v[0]), f2bf(v[1]), f2bf(v[2]), f2bf(v[3]) };
    *(u16x4*)(d + i) = o;
}

// ---------------- G1: xp = x @ Wp^T + bp  -> bf16 ----------------
__global__ __launch_bounds__(256) void kgemm_xp(
    const u16* __restrict__ xbf, const u16* __restrict__ wpb,
    const float* __restrict__ bp, u16* __restrict__ xpb)
{
    __shared__ u16 sA[4096], sB[4096];
    const int rowBase = blockIdx.y * 128, colBase = blockIdx.x * 128;
    f32x4 acc[4][4]; zero_acc(acc);
    mfma_loop(xbf + (size_t)rowBase * 1024, 1024,
              wpb + (size_t)colBase * 1024, 1024, 1024, sA, sB, acc);
    const int tid = threadIdx.x, l = tid & 63, wv = tid >> 6;
    const int wm = (wv >> 1) * 64, wn = (wv & 1) * 64, m16 = l & 15, k8 = l >> 4;
#pragma unroll
    for (int in = 0; in < 4; in++) {
        const int gc = colBase + wn + in * 16 + m16;
        const float bv = bp[gc];
#pragma unroll
        for (int im = 0; im < 4; im++) {
            const int gr = rowBase + wm + im * 16 + k8 * 4;
#pragma unroll
            for (int r = 0; r < 4; r++)
                xpb[(size_t)(gr + r) * 512 + gc] = f2bf(acc[im][in][r] + bv);
        }
    }
}

// ---------------- G2: h1[t,k] = relu(xg @ W1^T + b1) -> bf16 ----------------
__global__ __launch_bounds__(256) void kgemm_h1(
    const u16* __restrict__ xpb, const u16* __restrict__ w1b,
    const float* __restrict__ opb1, u16* __restrict__ h1b)
{
    __shared__ u16 sA[4096], sB[4096];
    const int seg = blockIdx.z, t = seg / 3;
    const int rowBase = blockIdx.y * 128, colBase = blockIdx.x * 128;
    f32x4 acc[4][4]; zero_acc(acc);
    // A row gi -> memory row gi*12 + t  (pitch 12*512)
    mfma_loop(xpb + (size_t)rowBase * 6144 + (size_t)t * 512, 6144,
              w1b + (size_t)seg * 262144 + (size_t)colBase * 512, 512, 512, sA, sB, acc);
    const int tid = threadIdx.x, l = tid & 63, wv = tid >> 6;
    const int wm = (wv >> 1) * 64, wn = (wv & 1) * 64, m16 = l & 15, k8 = l >> 4;
    u16* hseg = h1b + (size_t)seg * 524288;
#pragma unroll
    for (int in = 0; in < 4; in++) {
        const int gc = colBase + wn + in * 16 + m16;
        const float bv = opb1[seg * 512 + gc];
#pragma unroll
        for (int im = 0; im < 4; im++) {
            const int gr = rowBase + wm + im * 16 + k8 * 4;
#pragma unroll
            for (int r = 0; r < 4; r++)
                hseg[(size_t)(gr + r) * 512 + gc] = f2bf(fmaxf(acc[im][in][r] + bv, 0.f));
        }
    }
}

// ------- G3: out[t] = sum_k w[t,k]*relu(h1 @ W2^T + b2) -> f32 (d_out) + bf16 -------
__global__ __launch_bounds__(256) void kgemm_out(
    const u16* __restrict__ h1b, const u16* __restrict__ w2b,
    const float* __restrict__ opb2, const float* __restrict__ wbuf,
    float* __restrict__ outF, u16* __restrict__ outb)
{
    __shared__ u16 sA[4096], sB[4096];
    const int t = blockIdx.z;
    const int rowBase = blockIdx.y * 128, colBase = blockIdx.x * 128;
    const int tid = threadIdx.x, l = tid & 63, wv = tid >> 6;
    const int wm = (wv >> 1) * 64, wn = (wv & 1) * 64, m16 = l & 15, k8 = l >> 4;
    float oac[4][4][4];
#pragma unroll
    for (int i = 0; i < 4; i++)
#pragma unroll
        for (int j = 0; j < 4; j++)
#pragma unroll
            for (int r = 0; r < 4; r++) oac[i][j][r] = 0.f;

    for (int kk = 0; kk < 3; kk++) {
        const int seg = t * 3 + kk;
        f32x4 acc[4][4]; zero_acc(acc);
        mfma_loop(h1b + ((size_t)seg * 1024 + rowBase) * 512, 512,
                  w2b + (size_t)seg * 262144 + (size_t)colBase * 512, 512, 512, sA, sB, acc);
        const float wk = wbuf[seg];
#pragma unroll
        for (int in = 0; in < 4; in++) {
            const float bv = opb2[seg * 512 + colBase + wn + in * 16 + m16];
#pragma unroll
            for (int im = 0; im < 4; im++)
#pragma unroll
                for (int r = 0; r < 4; r++)
                    oac[im][in][r] += wk * fmaxf(acc[im][in][r] + bv, 0.f);
        }
    }
#pragma unroll
    for (int im = 0; im < 4; im++)
#pragma unroll
        for (int r = 0; r < 4; r++) {
            const int gi = rowBase + wm + im * 16 + k8 * 4 + r;
            const size_t b = (size_t)gi * 12 + t;   // scatter back to patch order
#pragma unroll
            for (int in = 0; in < 4; in++) {
                const int gc = colBase + wn + in * 16 + m16;
                const float v = oac[im][in][r];
                outF[b * 512 + gc] = v;
                outb[b * 512 + gc] = f2bf(v);
            }
        }
}

// ---------------- G4: pred = out @ phW^T + phb -> f32 ----------------
__global__ __launch_bounds__(256) void kgemm_pred(
    const u16* __restrict__ outb, const u16* __restrict__ phwb,
    const float* __restrict__ phb, float* __restrict__ outPred)
{
    __shared__ u16 sA[4096], sB[4096];
    const int rowBase = blockIdx.y * 128, colBase = blockIdx.x * 128;
    f32x4 acc[4][4]; zero_acc(acc);
    mfma_loop(outb + (size_t)rowBase * 512, 512,
              phwb + (size_t)colBase * 512, 512, 512, sA, sB, acc);
    const int tid = threadIdx.x, l = tid & 63, wv = tid >> 6;
    const int wm = (wv >> 1) * 64, wn = (wv & 1) * 64, m16 = l & 15, k8 = l >> 4;
#pragma unroll
    for (int in = 0; in < 4; in++) {
        const int gc = colBase + wn + in * 16 + m16;
        const float bv = phb[gc];
#pragma unroll
        for (int im = 0; im < 4; im++) {
            const int gr = rowBase + wm + im * 16 + k8 * 4;
#pragma unroll
            for (int r = 0; r < 4; r++)
                outPred[(size_t)(gr + r) * 1024 + gc] = acc[im][in][r] + bv;
        }
    }
}

// ---------------- G5: rh = relu(out @ rW1[:, :512]^T + bias_rh[b%12]) -> bf16 ----------------
__global__ __launch_bounds__(256) void kgemm_rh(
    const u16* __restrict__ outb, const u16* __restrict__ rw1b,
    const float* __restrict__ bias_rh, u16* __restrict__ rhb)
{
    __shared__ u16 sA[4096], sB[4096];
    const int rowBase = blockIdx.y * 128, colBase = blockIdx.x * 128;
    f32x4 acc[4][4]; zero_acc(acc);
    mfma_loop(outb + (size_t)rowBase * 512, 512,
              rw1b + (size_t)colBase * 512, 512, 512, sA, sB, acc);
    const int tid = threadIdx.x, l = tid & 63, wv = tid >> 6;
    const int wm = (wv >> 1) * 64, wn = (wv & 1) * 64, m16 = l & 15, k8 = l >> 4;
#pragma unroll
    for (int in = 0; in < 4; in++) {
        const int gc = colBase + wn + in * 16 + m16;
#pragma unroll
        for (int im = 0; im < 4; im++) {
            const int gr = rowBase + wm + im * 16 + k8 * 4;
#pragma unroll
            for (int r = 0; r < 4; r++) {
                const int b = gr + r;
                const float bv = bias_rh[(b % 12) * 512 + gc];
                rhb[(size_t)b * 512 + gc] = f2bf(fmaxf(acc[im][in][r] + bv, 0.f));
            }
        }
    }
}

// ---------------- per-row reductions -> 5 per-temper accumulators ----------------
__global__ __launch_bounds__(256) void rowred(
    const float* __restrict__ outF, const u16* __restrict__ xpb,
    const float* __restrict__ noise, float* __restrict__ acc5)
{
    const int tid = threadIdx.x, l = tid & 63, wv = tid >> 6;
    const int t = blockIdx.x % 12, grp = blockIdx.x / 12;
    const size_t b = (size_t)(grp * 4 + wv) * 12 + t;
    f32x8 ov = *(const f32x8*)(outF + b * 512 + l * 8);
    f32x8 nv = *(const f32x8*)(noise + b * 512 + l * 8);
    u16x8 xv = *(const u16x8*)(xpb + b * 512 + l * 8);
    float s1 = 0, s2 = 0, s3 = 0, s4 = 0;
#pragma unroll
    for (int j = 0; j < 8; j++) {
        float xg = bf2f(xv[j]);
        float o = ov[j];
        float d = o - xg;
        s1 += d * d; s2 += xg * xg; s3 += fabsf(o); s4 += nv[j] * nv[j];
    }
#pragma unroll
    for (int off = 32; off > 0; off >>= 1) {
        s1 += __shfl_xor(s1, off);
        s2 += __shfl_xor(s2, off);
        s3 += __shfl_xor(s3, off);
        s4 += __shfl_xor(s4, off);
    }
    __shared__ float part[4][5];
    if (l == 0) { part[wv][0]=s1; part[wv][1]=s2; part[wv][2]=s3; part[wv][3]=s4; part[wv][4]=s1*s1; }
    __syncthreads();
    if (tid < 5) {
        float v = part[0][tid] + part[1][tid] + part[2][tid] + part[3][tid];
        atomicAdd(acc5 + tid * 12 + t, v);
    }
}

// ---------------- signals -> decision (d_out) + folded routing bias ----------------
__global__ __launch_bounds__(256) void sig_kernel(
    const float* __restrict__ op_logits, const float* __restrict__ id_emb,
    const float* __restrict__ rW1, const float* __restrict__ rb1,
    const float* __restrict__ gW1, const float* __restrict__ gb1,
    const float* __restrict__ gW2, const float* __restrict__ gb2,
    const float* __restrict__ acc5, float* __restrict__ bias_rh,
    float* __restrict__ outDec)
{
    const int t = blockIdx.x, tid = threadIdx.x;
    __shared__ float sig[7], ex7[7], gch[512], red[256];
    if (tid == 0) {
        float l0 = op_logits[t*3+0], l1 = op_logits[t*3+1], l2 = op_logits[t*3+2];
        float mx = fmaxf(l0, fmaxf(l1, l2));
        float e0 = expf(l0-mx), e1 = expf(l1-mx), e2 = expf(l2-mx);
        float es = e0 + e1 + e2;
        float w0 = e0/es, w1 = e1/es, w2 = e2/es;
        float mean = (w0 + w1 + w2) * (1.f/3.f);
        float var = ((w0-mean)*(w0-mean) + (w1-mean)*(w1-mean) + (w2-mean)*(w2-mean)) * 0.5f;
        float conflict = sqrtf(var);
        float inv_s = 1.f / (w0 + w1 + w2 + 1e-6f);
        float u0 = w0*inv_s, u1 = w1*inv_s, u2 = w2*inv_s;
        float ent = -(u0*logf(fmaxf(u0,1e-6f)) + u1*logf(fmaxf(u1,1e-6f)) + u2*logf(fmaxf(u2,1e-6f)));
        const float inv = 1.f / (1024.f * 512.f);
        float plast = acc5[0*12+t] * inv;            // pred_err mean == last_plasticity
        float nov   = acc5[1*12+t] * inv;
        float spars = acc5[2*12+t] * inv;
        float plasticity = 1e-4f * acc5[3*12+t] * inv;
        float pe2 = acc5[4*12+t] * (1.f / (1024.f * 512.f * 512.f));
        float na = 0.01f * plast;
        float rvar = pe2 - 2.f*na*plast + na*na;
        sig[0]=plasticity; sig[1]=nov; sig[2]=plast; sig[3]=ent; sig[4]=spars; sig[5]=-plast; sig[6]=rvar;
        ex7[0]=id_emb[t*4+0]; ex7[1]=id_emb[t*4+1]; ex7[2]=id_emb[t*4+2]; ex7[3]=id_emb[t*4+3];
        ex7[4]=nov; ex7[5]=conflict; ex7[6]=plast;
    }
    __syncthreads();
    for (int h = tid; h < 512; h += 256) {
        float a = gb1[t*512 + h];
#pragma unroll
        for (int j = 0; j < 7; j++) a += gW1[(t*512 + h)*7 + j] * sig[j];
        gch[h] = fmaxf(a, 0.f);
        float bb = rb1[h];
#pragma unroll
        for (int e = 0; e < 7; e++) bb += ex7[e] * rW1[(size_t)h * 519 + 512 + e];
        bias_rh[t*512 + h] = bb;
    }
    __syncthreads();
    float p0 = 0.f, p1 = 0.f;
    for (int h = tid; h < 512; h += 256) {
        p0 += gW2[(t*2 + 0)*512 + h] * gch[h];
        p1 += gW2[(t*2 + 1)*512 + h] * gch[h];
    }
    red[tid] = p0; __syncthreads();
    for (int s = 128; s > 0; s >>= 1) { if (tid < s) red[tid] += red[tid + s]; __syncthreads(); }
    if (tid == 0) outDec[t*2 + 0] = red[0] + gb2[t*2 + 0];
    __syncthreads();
    red[tid] = p1; __syncthreads();
    for (int s = 128; s > 0; s >>= 1) { if (tid < s) red[tid] += red[tid + s]; __syncthreads(); }
    if (tid == 0) outDec[t*2 + 1] = red[0] + gb2[t*2 + 1];
}

// ---------------- logits = rh @ rW2^T + rb2 (one wave per row) ----------------
__global__ __launch_bounds__(256) void logits_kernel(
    const u16* __restrict__ rhb, const float* __restrict__ rW2,
    const float* __restrict__ rb2, float* __restrict__ outLg)
{
    __shared__ float T2[512 * 13];
    __shared__ float rb2s[16];
    const int tid = threadIdx.x;
    for (int i = tid; i < 6656; i += 256) {
        int o = i >> 9, j = i & 511;
        T2[j * 13 + o] = rW2[i];    // transposed+13-pitch: conflict-free reads
    }
    if (tid < 13) rb2s[tid] = rb2[tid];
    __syncthreads();
    const int l = tid & 63, wv = tid >> 6;
    const size_t b = (size_t)blockIdx.x * 4 + wv;
    const u16* rrow = rhb + b * 512;
    float rv[8];
#pragma unroll
    for (int jj = 0; jj < 8; jj++) rv[jj] = bf2f(rrow[l + 64 * jj]);
    float p[13];
#pragma unroll
    for (int o = 0; o < 13; o++) p[o] = 0.f;
#pragma unroll
    for (int jj = 0; jj < 8; jj++) {
        const float* tp = T2 + (l + 64 * jj) * 13;
#pragma unroll
        for (int o = 0; o < 13; o++) p[o] += rv[jj] * tp[o];
    }
#pragma unroll
    for (int o = 0; o < 13; o++) {
#pragma unroll
        for (int off = 32; off > 0; off >>= 1) p[o] += __shfl_xor(p[o], off);
    }
    if (l == 0) {
        float* orow = outLg + b * 13;
#pragma unroll
        for (int o = 0; o < 13; o++) orow[o] = p[o] + rb2s[o];
    }
}

extern "C" void kernel_launch(void* const* d_in, const int* in_sizes, int n_in,
                              void* d_out, int out_size, void* d_ws, size_t ws_size,
                              hipStream_t stream)
{
    const float* x         = (const float*)d_in[0];
    const float* Wp        = (const float*)d_in[1];
    const float* bp        = (const float*)d_in[2];
    const float* opW1      = (const float*)d_in[3];
    const float* opb1      = (const float*)d_in[4];
    const float* opW2      = (const float*)d_in[5];
    const float* opb2      = (const float*)d_in[6];
    const float* op_logits = (const float*)d_in[7];
    const float* id_emb    = (const float*)d_in[8];
    const float* rW1       = (const float*)d_in[9];
    const float* rb1       = (const float*)d_in[10];
    const float* rW2       = (const float*)d_in[11];
    const float* rb2       = (const float*)d_in[12];
    const float* gW1       = (const float*)d_in[13];
    const float* gb1       = (const float*)d_in[14];
    const float* gW2       = (const float*)d_in[15];
    const float* gb2       = (const float*)d_in[16];
    const float* phW       = (const float*)d_in[17];
    const float* phb       = (const float*)d_in[18];
    const float* noise     = (const float*)d_in[19];

    char* ws = (char*)d_ws;
    float* wbuf    = (float*)(ws + WS_W);
    float* acc5    = (float*)(ws + WS_ACC);
    float* bias_rh = (float*)(ws + WS_BIASRH);
    u16* wpb  = (u16*)(ws + WS_WPB);
    u16* phwb = (u16*)(ws + WS_PHWB);
    u16* rw1b = (u16*)(ws + WS_RW1B);
    u16* w1b  = (u16*)(ws + WS_W1B);
    u16* w2b  = (u16*)(ws + WS_W2B);
    u16* xpb  = (u16*)(ws + WS_XPB);
    u16* h1b  = (u16*)(ws + WS_H1B);
    u16* xbf  = (u16*)(ws + WS_XBF);
    u16* outb = (u16*)(ws + WS_OUTB);
    u16* rhb  = (u16*)(ws + WS_RHB);

    float* outF    = (float*)d_out;
    float* outLg   = outF + OUT_LG;
    float* outPred = outF + OUT_PRED;
    float* outDec  = outF + OUT_DEC;

    hipMemsetAsync(acc5, 0, 60 * sizeof(float), stream);
    cvt6<<<32000, 256, 0, stream>>>(x, xbf, opW1, w1b, opW2, w2b, Wp, wpb,
                                    phW, phwb, rW1, rw1b, op_logits, wbuf);
    kgemm_xp  <<<dim3(4, 96),    256, 0, stream>>>(xbf, wpb, bp, xpb);
    kgemm_h1  <<<dim3(4, 8, 36), 256, 0, stream>>>(xpb, w1b, opb1, h1b);
    kgemm_out <<<dim3(4, 8, 12), 256, 0, stream>>>(h1b, w2b, opb2, wbuf, outF, outb);
    kgemm_pred<<<dim3(8, 96),    256, 0, stream>>>(outb, phwb, phb, outPred);
    rowred    <<<3072,           256, 0, stream>>>(outF, xpb, noise, acc5);
    sig_kernel<<<12,             256, 0, stream>>>(op_logits, id_emb, rW1, rb1, gW1, gb1,
                                                   gW2, gb2, acc5, bias_rh, outDec);
    kgemm_rh  <<<dim3(4, 96),    256, 0, stream>>>(outb, rw1b, bias_rh, rhb);
    logits_kernel<<<3072,        256, 0, stream>>>(rhb, rW2, rb2, outLg);
}

// Round 2
// 424.088 us; speedup vs baseline: 1.1308x; 1.1308x over previous
//
#include <hip/hip_runtime.h>

typedef unsigned short u16;
typedef float f32x4 __attribute__((ext_vector_type(4)));
typedef float f32x8 __attribute__((ext_vector_type(8)));
typedef u16   u16x4 __attribute__((ext_vector_type(4)));
typedef u16   u16x8 __attribute__((ext_vector_type(8)));
typedef __bf16 bf16x8 __attribute__((ext_vector_type(8)));

// ---------------- workspace layout (bytes) ----------------
// peak ~110.5 MB; x_bf region is reused for out_bf/rh_bf after G1;
// opW1-bf16 region is reused for rowred partials after kgemm_h1.
#define WS_W       0u            // w softmax [12*3] f32
#define WS_ACC     256u          // (unused)
#define WS_BIASRH  512u          // [12*512] f32 = 24576B
#define WS_WPB     25600u        // Wp bf16 [512*1024]
#define WS_PHWB    1074176u      // phW bf16 [1024*512]
#define WS_RW1B    2122752u      // rW1[:, :512] bf16 [512*512]
#define WS_W1B     2647040u      // opW1 bf16 [36*512*512]; partials alias (dead after h1)
#define WS_W2B     21521408u     // opW2 bf16 [36*512*512]
#define WS_XPB     40395776u     // xp bf16 [12288*512]
#define WS_H1B     52978688u     // h1 bf16 [36*1024*512]
#define WS_XBF     90727424u     // x bf16 [12288*1024]   (dead after G1)
#define WS_OUTB    90727424u     // out bf16 [12288*512]  (aliases XBF lo)
#define WS_RHB     103310336u    // rh bf16 [12288*512]   (aliases XBF hi)

#define OUT_LG   6291456
#define OUT_PRED 6451200
#define OUT_DEC  19034112

__device__ __forceinline__ u16 f2bf(float f) {
    unsigned u = __builtin_bit_cast(unsigned, f);
    return (u16)((u + 0x7FFFu + ((u >> 16) & 1u)) >> 16);
}
__device__ __forceinline__ float bf2f(u16 h) {
    return __builtin_bit_cast(float, (unsigned)h << 16);
}

typedef __attribute__((address_space(1))) void* gas1p;
typedef __attribute__((address_space(3))) void* las3p;
__device__ __forceinline__ void gload16(const u16* g, u16* l) {
    __builtin_amdgcn_global_load_lds((gas1p)(unsigned long long)g,
                                     (las3p)(unsigned)(unsigned long long)l,
                                     16, 0, 0);
}

__device__ __forceinline__ void zero_acc(f32x4 (&a)[4][4]) {
#pragma unroll
    for (int i = 0; i < 4; i++)
#pragma unroll
        for (int j = 0; j < 4; j++)
            a[i][j] = (f32x4){0.f, 0.f, 0.f, 0.f};
}

// 128x128 tile, BK=32, 4 waves, each wave 64x64 via 4x4 mfma_16x16x32_bf16.
// Computes C = A * B^T : A rows pitch pa, B rows pitch pb (both bf16 [*, K]).
__device__ __forceinline__ void mfma_loop(
    const u16* __restrict__ Ab, size_t pa,
    const u16* __restrict__ Bb, size_t pb,
    int K, u16* sA, u16* sB, f32x4 (&acc)[4][4])
{
    const int tid = threadIdx.x;
    const int l = tid & 63, wv = tid >> 6;
    const int wm = (wv >> 1) * 64, wn = (wv & 1) * 64;
    const int m16 = l & 15, k8 = l >> 4;
    const int kc = (tid & 3) * 8;
    const size_t ra0 = (size_t)(tid >> 2) * pa + kc;
    const size_t ra1 = ra0 + 64 * pa;
    const size_t rb0 = (size_t)(tid >> 2) * pb + kc;
    const size_t rb1 = rb0 + 64 * pb;
    u16* dA0 = sA + tid * 8;          u16* dA1 = sA + (tid + 256) * 8;
    u16* dB0 = sB + tid * 8;          u16* dB1 = sB + (tid + 256) * 8;
    const int aO = (wm + m16) * 32 + k8 * 8;
    const int bO = (wn + m16) * 32 + k8 * 8;
    for (int kt = 0; kt < K; kt += 32) {
        __syncthreads();
        gload16(Ab + ra0 + kt, dA0);
        gload16(Ab + ra1 + kt, dA1);
        gload16(Bb + rb0 + kt, dB0);
        gload16(Bb + rb1 + kt, dB1);
        __syncthreads();
        bf16x8 af[4], bv[4];
#pragma unroll
        for (int i = 0; i < 4; i++) af[i] = *(const bf16x8*)(sA + aO + i * 512);
#pragma unroll
        for (int i = 0; i < 4; i++) bv[i] = *(const bf16x8*)(sB + bO + i * 512);
#pragma unroll
        for (int i = 0; i < 4; i++)
#pragma unroll
            for (int j = 0; j < 4; j++)
                acc[i][j] = __builtin_amdgcn_mfma_f32_16x16x32_bf16(af[i], bv[j], acc[i][j], 0, 0, 0);
    }
}

// ---------------- conversion + softmax(w) ----------------
__global__ __launch_bounds__(256) void cvt6(
    const float* __restrict__ x,    u16* __restrict__ xbf,
    const float* __restrict__ opW1, u16* __restrict__ w1b,
    const float* __restrict__ opW2, u16* __restrict__ w2b,
    const float* __restrict__ Wp,   u16* __restrict__ wpb,
    const float* __restrict__ phW,  u16* __restrict__ phwb,
    const float* __restrict__ rW1,  u16* __restrict__ rw1b,
    const float* __restrict__ op_logits, float* __restrict__ wbuf)
{
    if (blockIdx.x == 0 && threadIdx.x < 12) {
        const int t = threadIdx.x;
        float l0 = op_logits[t*3+0], l1 = op_logits[t*3+1], l2 = op_logits[t*3+2];
        float mx = fmaxf(l0, fmaxf(l1, l2));
        float e0 = expf(l0-mx), e1 = expf(l1-mx), e2 = expf(l2-mx);
        float inv = 1.f / (e0 + e1 + e2);
        wbuf[t*3+0] = e0*inv; wbuf[t*3+1] = e1*inv; wbuf[t*3+2] = e2*inv;
    }
    int i = (blockIdx.x * 256 + threadIdx.x) * 4;
    const float* s; u16* d;
    if (i < 12582912)                 { s = x;    d = xbf;  }
    else if ((i -= 12582912) < 9437184) { s = opW1; d = w1b; }
    else if ((i -= 9437184)  < 9437184) { s = opW2; d = w2b; }
    else if ((i -= 9437184)  < 524288)  { s = Wp;   d = wpb; }
    else if ((i -= 524288)   < 524288)  { s = phW;  d = phwb; }
    else {
        i -= 524288;  // [0, 262144): rW1 cols 0..511 of 519
        int row = i >> 9, j = i & 511;
        const float* sr = rW1 + (size_t)row * 519 + j;
        u16x4 o = { f2bf(sr[0]), f2bf(sr[1]), f2bf(sr[2]), f2bf(sr[3]) };
        *(u16x4*)(rw1b + i) = o;
        return;
    }
    f32x4 v = *(const f32x4*)(s + i);
    u16x4 o = { f2bf(v[0]), f2bf(v[1]), f2bf(v[2]), f2bf(v[3]) };
    *(u16x4*)(d + i) = o;
}

// ---------------- G1: xp = x @ Wp^T + bp  -> bf16 ----------------
__global__ __launch_bounds__(256) void kgemm_xp(
    const u16* __restrict__ xbf, const u16* __restrict__ wpb,
    const float* __restrict__ bp, u16* __restrict__ xpb)
{
    __shared__ u16 sA[4096], sB[4096];
    const int rowBase = blockIdx.y * 128, colBase = blockIdx.x * 128;
    f32x4 acc[4][4]; zero_acc(acc);
    mfma_loop(xbf + (size_t)rowBase * 1024, 1024,
              wpb + (size_t)colBase * 1024, 1024, 1024, sA, sB, acc);
    const int tid = threadIdx.x, l = tid & 63, wv = tid >> 6;
    const int wm = (wv >> 1) * 64, wn = (wv & 1) * 64, m16 = l & 15, k8 = l >> 4;
#pragma unroll
    for (int in = 0; in < 4; in++) {
        const int gc = colBase + wn + in * 16 + m16;
        const float bv = bp[gc];
#pragma unroll
        for (int im = 0; im < 4; im++) {
            const int gr = rowBase + wm + im * 16 + k8 * 4;
#pragma unroll
            for (int r = 0; r < 4; r++)
                xpb[(size_t)(gr + r) * 512 + gc] = f2bf(acc[im][in][r] + bv);
        }
    }
}

// ---------------- G2: h1[t,k] = relu(xg @ W1^T + b1) -> bf16 ----------------
__global__ __launch_bounds__(256) void kgemm_h1(
    const u16* __restrict__ xpb, const u16* __restrict__ w1b,
    const float* __restrict__ opb1, u16* __restrict__ h1b)
{
    __shared__ u16 sA[4096], sB[4096];
    const int seg = blockIdx.z, t = seg / 3;
    const int rowBase = blockIdx.y * 128, colBase = blockIdx.x * 128;
    f32x4 acc[4][4]; zero_acc(acc);
    // A row gi -> memory row gi*12 + t  (pitch 12*512)
    mfma_loop(xpb + (size_t)rowBase * 6144 + (size_t)t * 512, 6144,
              w1b + (size_t)seg * 262144 + (size_t)colBase * 512, 512, 512, sA, sB, acc);
    const int tid = threadIdx.x, l = tid & 63, wv = tid >> 6;
    const int wm = (wv >> 1) * 64, wn = (wv & 1) * 64, m16 = l & 15, k8 = l >> 4;
    u16* hseg = h1b + (size_t)seg * 524288;
#pragma unroll
    for (int in = 0; in < 4; in++) {
        const int gc = colBase + wn + in * 16 + m16;
        const float bv = opb1[seg * 512 + gc];
#pragma unroll
        for (int im = 0; im < 4; im++) {
            const int gr = rowBase + wm + im * 16 + k8 * 4;
#pragma unroll
            for (int r = 0; r < 4; r++)
                hseg[(size_t)(gr + r) * 512 + gc] = f2bf(fmaxf(acc[im][in][r] + bv, 0.f));
        }
    }
}

// ------- G3: out[t] = sum_k w[t,k]*relu(h1 @ W2^T + b2) -> f32 (d_out) + bf16 -------
__global__ __launch_bounds__(256) void kgemm_out(
    const u16* __restrict__ h1b, const u16* __restrict__ w2b,
    const float* __restrict__ opb2, const float* __restrict__ wbuf,
    float* __restrict__ outF, u16* __restrict__ outb)
{
    __shared__ u16 sA[4096], sB[4096];
    const int t = blockIdx.z;
    const int rowBase = blockIdx.y * 128, colBase = blockIdx.x * 128;
    const int tid = threadIdx.x, l = tid & 63, wv = tid >> 6;
    const int wm = (wv >> 1) * 64, wn = (wv & 1) * 64, m16 = l & 15, k8 = l >> 4;
    float oac[4][4][4];
#pragma unroll
    for (int i = 0; i < 4; i++)
#pragma unroll
        for (int j = 0; j < 4; j++)
#pragma unroll
            for (int r = 0; r < 4; r++) oac[i][j][r] = 0.f;

    for (int kk = 0; kk < 3; kk++) {
        const int seg = t * 3 + kk;
        f32x4 acc[4][4]; zero_acc(acc);
        mfma_loop(h1b + ((size_t)seg * 1024 + rowBase) * 512, 512,
                  w2b + (size_t)seg * 262144 + (size_t)colBase * 512, 512, 512, sA, sB, acc);
        const float wk = wbuf[seg];
#pragma unroll
        for (int in = 0; in < 4; in++) {
            const float bv = opb2[seg * 512 + colBase + wn + in * 16 + m16];
#pragma unroll
            for (int im = 0; im < 4; im++)
#pragma unroll
                for (int r = 0; r < 4; r++)
                    oac[im][in][r] += wk * fmaxf(acc[im][in][r] + bv, 0.f);
        }
    }
#pragma unroll
    for (int im = 0; im < 4; im++)
#pragma unroll
        for (int r = 0; r < 4; r++) {
            const int gi = rowBase + wm + im * 16 + k8 * 4 + r;
            const size_t b = (size_t)gi * 12 + t;   // scatter back to patch order
#pragma unroll
            for (int in = 0; in < 4; in++) {
                const int gc = colBase + wn + in * 16 + m16;
                const float v = oac[im][in][r];
                outF[b * 512 + gc] = v;
                outb[b * 512 + gc] = f2bf(v);
            }
        }
}

// ------- G4+G5 fused: pred = out @ phW^T + phb  |  rh = relu(out @ rW1^T + bias_rh) -------
__global__ __launch_bounds__(256) void kgemm_predrh(
    const u16* __restrict__ outb, const u16* __restrict__ phwb,
    const float* __restrict__ phb, const u16* __restrict__ rw1b,
    const float* __restrict__ bias_rh, float* __restrict__ outPred,
    u16* __restrict__ rhb)
{
    __shared__ u16 sA[4096], sB[4096];
    const int bz = blockIdx.x;                    // 0..7 pred colblocks, 8..11 rh
    const int rowBase = blockIdx.y * 128;
    const bool isPred = bz < 8;
    const int colBase = (isPred ? bz : bz - 8) * 128;
    const u16* Bb = isPred ? (phwb + (size_t)colBase * 512)
                           : (rw1b + (size_t)colBase * 512);
    f32x4 acc[4][4]; zero_acc(acc);
    mfma_loop(outb + (size_t)rowBase * 512, 512, Bb, 512, 512, sA, sB, acc);
    const int tid = threadIdx.x, l = tid & 63, wv = tid >> 6;
    const int wm = (wv >> 1) * 64, wn = (wv & 1) * 64, m16 = l & 15, k8 = l >> 4;
    if (isPred) {
#pragma unroll
        for (int in = 0; in < 4; in++) {
            const int gc = colBase + wn + in * 16 + m16;
            const float bv = phb[gc];
#pragma unroll
            for (int im = 0; im < 4; im++) {
                const int gr = rowBase + wm + im * 16 + k8 * 4;
#pragma unroll
                for (int r = 0; r < 4; r++)
                    outPred[(size_t)(gr + r) * 1024 + gc] = acc[im][in][r] + bv;
            }
        }
    } else {
#pragma unroll
        for (int in = 0; in < 4; in++) {
            const int gc = colBase + wn + in * 16 + m16;
#pragma unroll
            for (int im = 0; im < 4; im++) {
                const int gr = rowBase + wm + im * 16 + k8 * 4;
#pragma unroll
                for (int r = 0; r < 4; r++) {
                    const int b = gr + r;
                    const float bv = bias_rh[(b % 12) * 512 + gc];
                    rhb[(size_t)b * 512 + gc] = f2bf(fmaxf(acc[im][in][r] + bv, 0.f));
                }
            }
        }
    }
}

// ---------------- per-group streaming reductions -> per-wave partials ----------------
// Wave gw handles group gi==gw: rows b = gw*12 + t, t in [0,12). No atomics.
// partials[gw*60 + t*5 + s], s: 0=sum d^2, 1=sum xg^2, 2=sum|out|, 3=sum n^2, 4=(row d^2)^2
__global__ __launch_bounds__(256) void rowred(
    const float* __restrict__ outF, const u16* __restrict__ xpb,
    const float* __restrict__ noise, float* __restrict__ partials)
{
    const int tid = threadIdx.x, l = tid & 63, wv = tid >> 6;
    const int gw = blockIdx.x * 4 + wv;
    const size_t base = (size_t)gw * 12 * 512 + l * 8;
    float* pout = partials + (size_t)gw * 60;
#pragma unroll
    for (int t = 0; t < 12; t++) {
        const size_t off = base + (size_t)t * 512;
        f32x8 ov = *(const f32x8*)(outF + off);
        f32x8 nv = *(const f32x8*)(noise + off);
        u16x8 xv = *(const u16x8*)(xpb + off);
        float s1 = 0, s2 = 0, s3 = 0, s4 = 0;
#pragma unroll
        for (int j = 0; j < 8; j++) {
            float xg = bf2f(xv[j]);
            float o = ov[j];
            float d = o - xg;
            s1 += d * d; s2 += xg * xg; s3 += fabsf(o); s4 += nv[j] * nv[j];
        }
#pragma unroll
        for (int off2 = 32; off2 > 0; off2 >>= 1) {
            s1 += __shfl_xor(s1, off2);
            s2 += __shfl_xor(s2, off2);
            s3 += __shfl_xor(s3, off2);
            s4 += __shfl_xor(s4, off2);
        }
        if (l < 5) {
            float v = (l == 0) ? s1 : (l == 1) ? s2 : (l == 2) ? s3
                    : (l == 3) ? s4 : s1 * s1;
            pout[t * 5 + l] = v;
        }
    }
}

// ---------------- partial-reduce + signals -> decision (d_out) + folded routing bias ----------------
__global__ __launch_bounds__(256) void sig_kernel(
    const float* __restrict__ op_logits, const float* __restrict__ id_emb,
    const float* __restrict__ rW1, const float* __restrict__ rb1,
    const float* __restrict__ gW1, const float* __restrict__ gb1,
    const float* __restrict__ gW2, const float* __restrict__ gb2,
    const float* __restrict__ partials, float* __restrict__ bias_rh,
    float* __restrict__ outDec)
{
    const int t = blockIdx.x, tid = threadIdx.x;
    __shared__ float sig[7], ex7[7], gch[512], red[256], accv[5];
    float a[5] = {0.f, 0.f, 0.f, 0.f, 0.f};
    for (int g = tid; g < 1024; g += 256) {
        const float* p = partials + (size_t)g * 60 + t * 5;
#pragma unroll
        for (int s = 0; s < 5; s++) a[s] += p[s];
    }
#pragma unroll
    for (int s = 0; s < 5; s++) {
        red[tid] = a[s]; __syncthreads();
        for (int k = 128; k > 0; k >>= 1) { if (tid < k) red[tid] += red[tid + k]; __syncthreads(); }
        if (tid == 0) accv[s] = red[0];
        __syncthreads();
    }
    if (tid == 0) {
        float l0 = op_logits[t*3+0], l1 = op_logits[t*3+1], l2 = op_logits[t*3+2];
        float mx = fmaxf(l0, fmaxf(l1, l2));
        float e0 = expf(l0-mx), e1 = expf(l1-mx), e2 = expf(l2-mx);
        float es = e0 + e1 + e2;
        float w0 = e0/es, w1 = e1/es, w2 = e2/es;
        float mean = (w0 + w1 + w2) * (1.f/3.f);
        float var = ((w0-mean)*(w0-mean) + (w1-mean)*(w1-mean) + (w2-mean)*(w2-mean)) * 0.5f;
        float conflict = sqrtf(var);
        float inv_s = 1.f / (w0 + w1 + w2 + 1e-6f);
        float u0 = w0*inv_s, u1 = w1*inv_s, u2 = w2*inv_s;
        float ent = -(u0*logf(fmaxf(u0,1e-6f)) + u1*logf(fmaxf(u1,1e-6f)) + u2*logf(fmaxf(u2,1e-6f)));
        const float inv = 1.f / (1024.f * 512.f);
        float plast = accv[0] * inv;                 // pred_err mean == last_plasticity
        float nov   = accv[1] * inv;
        float spars = accv[2] * inv;
        float plasticity = 1e-4f * accv[3] * inv;
        float pe2 = accv[4] * (1.f / (1024.f * 512.f * 512.f));
        float na = 0.01f * plast;
        float rvar = pe2 - 2.f*na*plast + na*na;
        sig[0]=plasticity; sig[1]=nov; sig[2]=plast; sig[3]=ent; sig[4]=spars; sig[5]=-plast; sig[6]=rvar;
        ex7[0]=id_emb[t*4+0]; ex7[1]=id_emb[t*4+1]; ex7[2]=id_emb[t*4+2]; ex7[3]=id_emb[t*4+3];
        ex7[4]=nov; ex7[5]=conflict; ex7[6]=plast;
    }
    __syncthreads();
    for (int h = tid; h < 512; h += 256) {
        float aa = gb1[t*512 + h];
#pragma unroll
        for (int j = 0; j < 7; j++) aa += gW1[(t*512 + h)*7 + j] * sig[j];
        gch[h] = fmaxf(aa, 0.f);
        float bb = rb1[h];
#pragma unroll
        for (int e = 0; e < 7; e++) bb += ex7[e] * rW1[(size_t)h * 519 + 512 + e];
        bias_rh[t*512 + h] = bb;
    }
    __syncthreads();
    float p0 = 0.f, p1 = 0.f;
    for (int h = tid; h < 512; h += 256) {
        p0 += gW2[(t*2 + 0)*512 + h] * gch[h];
        p1 += gW2[(t*2 + 1)*512 + h] * gch[h];
    }
    red[tid] = p0; __syncthreads();
    for (int s = 128; s > 0; s >>= 1) { if (tid < s) red[tid] += red[tid + s]; __syncthreads(); }
    if (tid == 0) outDec[t*2 + 0] = red[0] + gb2[t*2 + 0];
    __syncthreads();
    red[tid] = p1; __syncthreads();
    for (int s = 128; s > 0; s >>= 1) { if (tid < s) red[tid] += red[tid + s]; __syncthreads(); }
    if (tid == 0) outDec[t*2 + 1] = red[0] + gb2[t*2 + 1];
}

// ---------------- logits = rh @ rW2^T + rb2 (one wave per row) ----------------
__global__ __launch_bounds__(256) void logits_kernel(
    const u16* __restrict__ rhb, const float* __restrict__ rW2,
    const float* __restrict__ rb2, float* __restrict__ outLg)
{
    __shared__ float T2[512 * 13];
    __shared__ float rb2s[16];
    const int tid = threadIdx.x;
    for (int i = tid; i < 6656; i += 256) {
        int o = i >> 9, j = i & 511;
        T2[j * 13 + o] = rW2[i];    // transposed+13-pitch: conflict-free reads
    }
    if (tid < 13) rb2s[tid] = rb2[tid];
    __syncthreads();
    const int l = tid & 63, wv = tid >> 6;
    const size_t b = (size_t)blockIdx.x * 4 + wv;
    const u16* rrow = rhb + b * 512;
    float rv[8];
#pragma unroll
    for (int jj = 0; jj < 8; jj++) rv[jj] = bf2f(rrow[l + 64 * jj]);
    float p[13];
#pragma unroll
    for (int o = 0; o < 13; o++) p[o] = 0.f;
#pragma unroll
    for (int jj = 0; jj < 8; jj++) {
        const float* tp = T2 + (l + 64 * jj) * 13;
#pragma unroll
        for (int o = 0; o < 13; o++) p[o] += rv[jj] * tp[o];
    }
#pragma unroll
    for (int o = 0; o < 13; o++) {
#pragma unroll
        for (int off = 32; off > 0; off >>= 1) p[o] += __shfl_xor(p[o], off);
    }
    if (l == 0) {
        float* orow = outLg + b * 13;
#pragma unroll
        for (int o = 0; o < 13; o++) orow[o] = p[o] + rb2s[o];
    }
}

extern "C" void kernel_launch(void* const* d_in, const int* in_sizes, int n_in,
                              void* d_out, int out_size, void* d_ws, size_t ws_size,
                              hipStream_t stream)
{
    const float* x         = (const float*)d_in[0];
    const float* Wp        = (const float*)d_in[1];
    const float* bp        = (const float*)d_in[2];
    const float* opW1      = (const float*)d_in[3];
    const float* opb1      = (const float*)d_in[4];
    const float* opW2      = (const float*)d_in[5];
    const float* opb2      = (const float*)d_in[6];
    const float* op_logits = (const float*)d_in[7];
    const float* id_emb    = (const float*)d_in[8];
    const float* rW1       = (const float*)d_in[9];
    const float* rb1       = (const float*)d_in[10];
    const float* rW2       = (const float*)d_in[11];
    const float* rb2       = (const float*)d_in[12];
    const float* gW1       = (const float*)d_in[13];
    const float* gb1       = (const float*)d_in[14];
    const float* gW2       = (const float*)d_in[15];
    const float* gb2       = (const float*)d_in[16];
    const float* phW       = (const float*)d_in[17];
    const float* phb       = (const float*)d_in[18];
    const float* noise     = (const float*)d_in[19];

    char* ws = (char*)d_ws;
    float* wbuf    = (float*)(ws + WS_W);
    float* bias_rh = (float*)(ws + WS_BIASRH);
    u16* wpb  = (u16*)(ws + WS_WPB);
    u16* phwb = (u16*)(ws + WS_PHWB);
    u16* rw1b = (u16*)(ws + WS_RW1B);
    u16* w1b  = (u16*)(ws + WS_W1B);
    u16* w2b  = (u16*)(ws + WS_W2B);
    u16* xpb  = (u16*)(ws + WS_XPB);
    u16* h1b  = (u16*)(ws + WS_H1B);
    u16* xbf  = (u16*)(ws + WS_XBF);
    u16* outb = (u16*)(ws + WS_OUTB);
    u16* rhb  = (u16*)(ws + WS_RHB);
    float* partials = (float*)(ws + WS_W1B);   // aliases w1b, dead after kgemm_h1

    float* outF    = (float*)d_out;
    float* outLg   = outF + OUT_LG;
    float* outPred = outF + OUT_PRED;
    float* outDec  = outF + OUT_DEC;

    cvt6<<<32000, 256, 0, stream>>>(x, xbf, opW1, w1b, opW2, w2b, Wp, wpb,
                                    phW, phwb, rW1, rw1b, op_logits, wbuf);
    kgemm_xp  <<<dim3(4, 96),    256, 0, stream>>>(xbf, wpb, bp, xpb);
    kgemm_h1  <<<dim3(4, 8, 36), 256, 0, stream>>>(xpb, w1b, opb1, h1b);
    kgemm_out <<<dim3(4, 8, 12), 256, 0, stream>>>(h1b, w2b, opb2, wbuf, outF, outb);
    rowred    <<<256,            256, 0, stream>>>(outF, xpb, noise, partials);
    sig_kernel<<<12,             256, 0, stream>>>(op_logits, id_emb, rW1, rb1, gW1, gb1,
                                                   gW2, gb2, partials, bias_rh, outDec);
    kgemm_predrh<<<dim3(12, 96), 256, 0, stream>>>(outb, phwb, phb, rw1b, bias_rh,
                                                   outPred, rhb);
    logits_kernel<<<3072,        256, 0, stream>>>(rhb, rW2, rb2, outLg);
}

// Round 3
// 398.685 us; speedup vs baseline: 1.2029x; 1.0637x over previous
//
#include <hip/hip_runtime.h>

typedef unsigned short u16;
typedef float f32x4 __attribute__((ext_vector_type(4)));
typedef float f32x8 __attribute__((ext_vector_type(8)));
typedef u16   u16x4 __attribute__((ext_vector_type(4)));
typedef u16   u16x8 __attribute__((ext_vector_type(8)));
typedef __bf16 bf16x8 __attribute__((ext_vector_type(8)));

// ---------------- workspace layout (bytes) ----------------
#define WS_W       0u            // w softmax [12*3] f32
#define WS_BIASRH  512u          // [12*512] f32 = 24576B
#define WS_WPB     25600u        // Wp bf16 [512*1024]
#define WS_PHWB    1074176u      // phW bf16 [1024*512]
#define WS_RW1B    2122752u      // rW1[:, :512] bf16 [512*512]
#define WS_W1B     2647040u      // opW1 bf16 [36*512*512]; partials alias (dead after h1)
#define WS_W2B     21521408u     // opW2 bf16 [36*512*512]
#define WS_XPB     40395776u     // xp bf16 [12288*512]
#define WS_H1B     52978688u     // h1 bf16 [36*1024*512]
#define WS_XBF     90727424u     // x bf16 [12288*1024]   (dead after G1)
#define WS_OUTB    90727424u     // out bf16 [12288*512]  (aliases XBF lo)
#define WS_RHB     103310336u    // rh bf16 [12288*512]   (aliases XBF hi)

#define OUT_LG   6291456
#define OUT_PRED 6451200
#define OUT_DEC  19034112

__device__ __forceinline__ u16 f2bf(float f) {
    unsigned u = __builtin_bit_cast(unsigned, f);
    return (u16)((u + 0x7FFFu + ((u >> 16) & 1u)) >> 16);
}
__device__ __forceinline__ float bf2f(u16 h) {
    return __builtin_bit_cast(float, (unsigned)h << 16);
}

typedef __attribute__((address_space(1))) void* gas1p;
typedef __attribute__((address_space(3))) void* las3p;
__device__ __forceinline__ void gload16(const u16* g, u16* l) {
    __builtin_amdgcn_global_load_lds((gas1p)(unsigned long long)g,
                                     (las3p)(unsigned)(unsigned long long)l,
                                     16, 0, 0);
}

__device__ __forceinline__ void zero_acc(f32x4 (&a)[4][4]) {
#pragma unroll
    for (int i = 0; i < 4; i++)
#pragma unroll
        for (int j = 0; j < 4; j++)
            a[i][j] = (f32x4){0.f, 0.f, 0.f, 0.f};
}

// 128x128 tile, BK=32, 4 waves (2x2 of 64x64). C = A * B^T.
__device__ __forceinline__ void mfma_loop(
    const u16* __restrict__ Ab, size_t pa,
    const u16* __restrict__ Bb, size_t pb,
    int K, u16* sA, u16* sB, f32x4 (&acc)[4][4])
{
    const int tid = threadIdx.x;
    const int l = tid & 63, wv = tid >> 6;
    const int wm = (wv >> 1) * 64, wn = (wv & 1) * 64;
    const int m16 = l & 15, k8 = l >> 4;
    const int kc = (tid & 3) * 8;
    const size_t ra0 = (size_t)(tid >> 2) * pa + kc;
    const size_t ra1 = ra0 + 64 * pa;
    const size_t rb0 = (size_t)(tid >> 2) * pb + kc;
    const size_t rb1 = rb0 + 64 * pb;
    u16* dA0 = sA + tid * 8;          u16* dA1 = sA + (tid + 256) * 8;
    u16* dB0 = sB + tid * 8;          u16* dB1 = sB + (tid + 256) * 8;
    const int aO = (wm + m16) * 32 + k8 * 8;
    const int bO = (wn + m16) * 32 + k8 * 8;
    for (int kt = 0; kt < K; kt += 32) {
        __syncthreads();
        gload16(Ab + ra0 + kt, dA0);
        gload16(Ab + ra1 + kt, dA1);
        gload16(Bb + rb0 + kt, dB0);
        gload16(Bb + rb1 + kt, dB1);
        __syncthreads();
        bf16x8 af[4], bv[4];
#pragma unroll
        for (int i = 0; i < 4; i++) af[i] = *(const bf16x8*)(sA + aO + i * 512);
#pragma unroll
        for (int i = 0; i < 4; i++) bv[i] = *(const bf16x8*)(sB + bO + i * 512);
#pragma unroll
        for (int i = 0; i < 4; i++)
#pragma unroll
            for (int j = 0; j < 4; j++)
                acc[i][j] = __builtin_amdgcn_mfma_f32_16x16x32_bf16(af[i], bv[j], acc[i][j], 0, 0, 0);
    }
}

// 64x128 tile, BK=32, 4 waves side-by-side in N (each 64M x 32N, 4x2 mfma).
// Gives 768-block grids (3.0 blocks/CU) for the M=12288, N=512 GEMMs.
__device__ __forceinline__ void mfma_loop64(
    const u16* __restrict__ Ab, size_t pa,
    const u16* __restrict__ Bb, size_t pb,
    int K, u16* sA, u16* sB, f32x4 (&acc)[4][2])
{
    const int tid = threadIdx.x;
    const int l = tid & 63, wv = tid >> 6;
    const int m16 = l & 15, k8 = l >> 4;
    const int kc = (tid & 3) * 8;
    const size_t ra0 = (size_t)(tid >> 2) * pa + kc;
    const size_t rb0 = (size_t)(tid >> 2) * pb + kc;
    const size_t rb1 = rb0 + 64 * pb;
    u16* dA0 = sA + tid * 8;
    u16* dB0 = sB + tid * 8;          u16* dB1 = sB + (tid + 256) * 8;
    const int aO = m16 * 32 + k8 * 8;
    const int bO = (wv * 32 + m16) * 32 + k8 * 8;
    for (int kt = 0; kt < K; kt += 32) {
        __syncthreads();
        gload16(Ab + ra0 + kt, dA0);
        gload16(Bb + rb0 + kt, dB0);
        gload16(Bb + rb1 + kt, dB1);
        __syncthreads();
        bf16x8 af[4], bv[2];
#pragma unroll
        for (int i = 0; i < 4; i++) af[i] = *(const bf16x8*)(sA + aO + i * 512);
#pragma unroll
        for (int j = 0; j < 2; j++) bv[j] = *(const bf16x8*)(sB + bO + j * 512);
#pragma unroll
        for (int i = 0; i < 4; i++)
#pragma unroll
            for (int j = 0; j < 2; j++)
                acc[i][j] = __builtin_amdgcn_mfma_f32_16x16x32_bf16(af[i], bv[j], acc[i][j], 0, 0, 0);
    }
}

// ---------------- conversion + softmax(w) ----------------
__global__ __launch_bounds__(256) void cvt6(
    const float* __restrict__ x,    u16* __restrict__ xbf,
    const float* __restrict__ opW1, u16* __restrict__ w1b,
    const float* __restrict__ opW2, u16* __restrict__ w2b,
    const float* __restrict__ Wp,   u16* __restrict__ wpb,
    const float* __restrict__ phW,  u16* __restrict__ phwb,
    const float* __restrict__ rW1,  u16* __restrict__ rw1b,
    const float* __restrict__ op_logits, float* __restrict__ wbuf)
{
    if (blockIdx.x == 0 && threadIdx.x < 12) {
        const int t = threadIdx.x;
        float l0 = op_logits[t*3+0], l1 = op_logits[t*3+1], l2 = op_logits[t*3+2];
        float mx = fmaxf(l0, fmaxf(l1, l2));
        float e0 = expf(l0-mx), e1 = expf(l1-mx), e2 = expf(l2-mx);
        float inv = 1.f / (e0 + e1 + e2);
        wbuf[t*3+0] = e0*inv; wbuf[t*3+1] = e1*inv; wbuf[t*3+2] = e2*inv;
    }
    int i = (blockIdx.x * 256 + threadIdx.x) * 4;
    const float* s; u16* d;
    if (i < 12582912)                 { s = x;    d = xbf;  }
    else if ((i -= 12582912) < 9437184) { s = opW1; d = w1b; }
    else if ((i -= 9437184)  < 9437184) { s = opW2; d = w2b; }
    else if ((i -= 9437184)  < 524288)  { s = Wp;   d = wpb; }
    else if ((i -= 524288)   < 524288)  { s = phW;  d = phwb; }
    else {
        i -= 524288;  // [0, 262144): rW1 cols 0..511 of 519
        int row = i >> 9, j = i & 511;
        const float* sr = rW1 + (size_t)row * 519 + j;
        u16x4 o = { f2bf(sr[0]), f2bf(sr[1]), f2bf(sr[2]), f2bf(sr[3]) };
        *(u16x4*)(rw1b + i) = o;
        return;
    }
    f32x4 v = *(const f32x4*)(s + i);
    u16x4 o = { f2bf(v[0]), f2bf(v[1]), f2bf(v[2]), f2bf(v[3]) };
    *(u16x4*)(d + i) = o;
}

// ---------------- G1: xp = x @ Wp^T + bp  -> bf16  (64x128 tiles, 768 blocks) ----------------
__global__ __launch_bounds__(256) void kgemm_xp(
    const u16* __restrict__ xbf, const u16* __restrict__ wpb,
    const float* __restrict__ bp, u16* __restrict__ xpb)
{
    __shared__ u16 sA[2048], sB[4096];
    const int rowBase = blockIdx.y * 64, colBase = blockIdx.x * 128;
    f32x4 acc[4][2];
#pragma unroll
    for (int i = 0; i < 4; i++)
#pragma unroll
        for (int j = 0; j < 2; j++) acc[i][j] = (f32x4){0.f,0.f,0.f,0.f};
    mfma_loop64(xbf + (size_t)rowBase * 1024, 1024,
                wpb + (size_t)colBase * 1024, 1024, 1024, sA, sB, acc);
    const int tid = threadIdx.x, l = tid & 63, wv = tid >> 6;
    const int m16 = l & 15, k8 = l >> 4;
#pragma unroll
    for (int in = 0; in < 2; in++) {
        const int gc = colBase + wv * 32 + in * 16 + m16;
        const float bv = bp[gc];
#pragma unroll
        for (int im = 0; im < 4; im++) {
            const int gr = rowBase + im * 16 + k8 * 4;
#pragma unroll
            for (int r = 0; r < 4; r++)
                xpb[(size_t)(gr + r) * 512 + gc] = f2bf(acc[im][in][r] + bv);
        }
    }
}

// ---------------- G2: h1[t,k] = relu(xg @ W1^T + b1) -> bf16 ----------------
__global__ __launch_bounds__(256) void kgemm_h1(
    const u16* __restrict__ xpb, const u16* __restrict__ w1b,
    const float* __restrict__ opb1, u16* __restrict__ h1b)
{
    __shared__ u16 sA[4096], sB[4096];
    const int seg = blockIdx.z, t = seg / 3;
    const int rowBase = blockIdx.y * 128, colBase = blockIdx.x * 128;
    f32x4 acc[4][4]; zero_acc(acc);
    // A row gi -> memory row gi*12 + t  (pitch 12*512)
    mfma_loop(xpb + (size_t)rowBase * 6144 + (size_t)t * 512, 6144,
              w1b + (size_t)seg * 262144 + (size_t)colBase * 512, 512, 512, sA, sB, acc);
    const int tid = threadIdx.x, l = tid & 63, wv = tid >> 6;
    const int wm = (wv >> 1) * 64, wn = (wv & 1) * 64, m16 = l & 15, k8 = l >> 4;
    u16* hseg = h1b + (size_t)seg * 524288;
#pragma unroll
    for (int in = 0; in < 4; in++) {
        const int gc = colBase + wn + in * 16 + m16;
        const float bv = opb1[seg * 512 + gc];
#pragma unroll
        for (int im = 0; im < 4; im++) {
            const int gr = rowBase + wm + im * 16 + k8 * 4;
#pragma unroll
            for (int r = 0; r < 4; r++)
                hseg[(size_t)(gr + r) * 512 + gc] = f2bf(fmaxf(acc[im][in][r] + bv, 0.f));
        }
    }
}

// ------- G3: out[t] = sum_k w[t,k]*relu(h1 @ W2^T + b2) -> f32 + bf16 (64x128, 768 blocks) -------
__global__ __launch_bounds__(256) void kgemm_out(
    const u16* __restrict__ h1b, const u16* __restrict__ w2b,
    const float* __restrict__ opb2, const float* __restrict__ wbuf,
    float* __restrict__ outF, u16* __restrict__ outb)
{
    __shared__ u16 sA[2048], sB[4096];
    const int t = blockIdx.z;
    const int rowBase = blockIdx.y * 64, colBase = blockIdx.x * 128;
    const int tid = threadIdx.x, l = tid & 63, wv = tid >> 6;
    const int m16 = l & 15, k8 = l >> 4;
    float oac[4][2][4];
#pragma unroll
    for (int i = 0; i < 4; i++)
#pragma unroll
        for (int j = 0; j < 2; j++)
#pragma unroll
            for (int r = 0; r < 4; r++) oac[i][j][r] = 0.f;

    for (int kk = 0; kk < 3; kk++) {
        const int seg = t * 3 + kk;
        f32x4 acc[4][2];
#pragma unroll
        for (int i = 0; i < 4; i++)
#pragma unroll
            for (int j = 0; j < 2; j++) acc[i][j] = (f32x4){0.f,0.f,0.f,0.f};
        mfma_loop64(h1b + ((size_t)seg * 1024 + rowBase) * 512, 512,
                    w2b + (size_t)seg * 262144 + (size_t)colBase * 512, 512, 512, sA, sB, acc);
        const float wk = wbuf[seg];
#pragma unroll
        for (int in = 0; in < 2; in++) {
            const float bv = opb2[seg * 512 + colBase + wv * 32 + in * 16 + m16];
#pragma unroll
            for (int im = 0; im < 4; im++)
#pragma unroll
                for (int r = 0; r < 4; r++)
                    oac[im][in][r] += wk * fmaxf(acc[im][in][r] + bv, 0.f);
        }
    }
#pragma unroll
    for (int im = 0; im < 4; im++)
#pragma unroll
        for (int r = 0; r < 4; r++) {
            const int gi = rowBase + im * 16 + k8 * 4 + r;
            const size_t b = (size_t)gi * 12 + t;   // scatter back to patch order
#pragma unroll
            for (int in = 0; in < 2; in++) {
                const int gc = colBase + wv * 32 + in * 16 + m16;
                const float v = oac[im][in][r];
                outF[b * 512 + gc] = v;
                outb[b * 512 + gc] = f2bf(v);
            }
        }
}

// ------- G4+G5 fused: pred = out @ phW^T + phb  |  rh = relu(out @ rW1^T + bias_rh) -------
__global__ __launch_bounds__(256) void kgemm_predrh(
    const u16* __restrict__ outb, const u16* __restrict__ phwb,
    const float* __restrict__ phb, const u16* __restrict__ rw1b,
    const float* __restrict__ bias_rh, float* __restrict__ outPred,
    u16* __restrict__ rhb)
{
    __shared__ u16 sA[4096], sB[4096];
    const int bz = blockIdx.x;                    // 0..7 pred colblocks, 8..11 rh
    const int rowBase = blockIdx.y * 128;
    const bool isPred = bz < 8;
    const int colBase = (isPred ? bz : bz - 8) * 128;
    const u16* Bb = isPred ? (phwb + (size_t)colBase * 512)
                           : (rw1b + (size_t)colBase * 512);
    f32x4 acc[4][4]; zero_acc(acc);
    mfma_loop(outb + (size_t)rowBase * 512, 512, Bb, 512, 512, sA, sB, acc);
    const int tid = threadIdx.x, l = tid & 63, wv = tid >> 6;
    const int wm = (wv >> 1) * 64, wn = (wv & 1) * 64, m16 = l & 15, k8 = l >> 4;
    if (isPred) {
#pragma unroll
        for (int in = 0; in < 4; in++) {
            const int gc = colBase + wn + in * 16 + m16;
            const float bv = phb[gc];
#pragma unroll
            for (int im = 0; im < 4; im++) {
                const int gr = rowBase + wm + im * 16 + k8 * 4;
#pragma unroll
                for (int r = 0; r < 4; r++)
                    outPred[(size_t)(gr + r) * 1024 + gc] = acc[im][in][r] + bv;
            }
        }
    } else {
#pragma unroll
        for (int in = 0; in < 4; in++) {
            const int gc = colBase + wn + in * 16 + m16;
#pragma unroll
            for (int im = 0; im < 4; im++) {
                const int gr = rowBase + wm + im * 16 + k8 * 4;
#pragma unroll
                for (int r = 0; r < 4; r++) {
                    const int b = gr + r;
                    const float bv = bias_rh[(b % 12) * 512 + gc];
                    rhb[(size_t)b * 512 + gc] = f2bf(fmaxf(acc[im][in][r] + bv, 0.f));
                }
            }
        }
    }
}

// ---------------- per-group streaming reductions -> per-wave partials ----------------
__global__ __launch_bounds__(256) void rowred(
    const float* __restrict__ outF, const u16* __restrict__ xpb,
    const float* __restrict__ noise, float* __restrict__ partials)
{
    const int tid = threadIdx.x, l = tid & 63, wv = tid >> 6;
    const int gw = blockIdx.x * 4 + wv;
    const size_t base = (size_t)gw * 12 * 512 + l * 8;
    float* pout = partials + (size_t)gw * 60;
#pragma unroll
    for (int t = 0; t < 12; t++) {
        const size_t off = base + (size_t)t * 512;
        f32x8 ov = *(const f32x8*)(outF + off);
        f32x8 nv = *(const f32x8*)(noise + off);
        u16x8 xv = *(const u16x8*)(xpb + off);
        float s1 = 0, s2 = 0, s3 = 0, s4 = 0;
#pragma unroll
        for (int j = 0; j < 8; j++) {
            float xg = bf2f(xv[j]);
            float o = ov[j];
            float d = o - xg;
            s1 += d * d; s2 += xg * xg; s3 += fabsf(o); s4 += nv[j] * nv[j];
        }
#pragma unroll
        for (int off2 = 32; off2 > 0; off2 >>= 1) {
            s1 += __shfl_xor(s1, off2);
            s2 += __shfl_xor(s2, off2);
            s3 += __shfl_xor(s3, off2);
            s4 += __shfl_xor(s4, off2);
        }
        if (l < 5) {
            float v = (l == 0) ? s1 : (l == 1) ? s2 : (l == 2) ? s3
                    : (l == 3) ? s4 : s1 * s1;
            pout[t * 5 + l] = v;
        }
    }
}

// ---------------- partial-reduce + signals -> decision + folded routing bias ----------------
__global__ __launch_bounds__(256) void sig_kernel(
    const float* __restrict__ op_logits, const float* __restrict__ id_emb,
    const float* __restrict__ rW1, const float* __restrict__ rb1,
    const float* __restrict__ gW1, const float* __restrict__ gb1,
    const float* __restrict__ gW2, const float* __restrict__ gb2,
    const float* __restrict__ partials, float* __restrict__ bias_rh,
    float* __restrict__ outDec)
{
    const int t = blockIdx.x, tid = threadIdx.x;
    __shared__ float sig[7], ex7[7], gch[512], red[256], accv[5];
    float a[5] = {0.f, 0.f, 0.f, 0.f, 0.f};
    for (int g = tid; g < 1024; g += 256) {
        const float* p = partials + (size_t)g * 60 + t * 5;
#pragma unroll
        for (int s = 0; s < 5; s++) a[s] += p[s];
    }
#pragma unroll
    for (int s = 0; s < 5; s++) {
        red[tid] = a[s]; __syncthreads();
        for (int k = 128; k > 0; k >>= 1) { if (tid < k) red[tid] += red[tid + k]; __syncthreads(); }
        if (tid == 0) accv[s] = red[0];
        __syncthreads();
    }
    if (tid == 0) {
        float l0 = op_logits[t*3+0], l1 = op_logits[t*3+1], l2 = op_logits[t*3+2];
        float mx = fmaxf(l0, fmaxf(l1, l2));
        float e0 = expf(l0-mx), e1 = expf(l1-mx), e2 = expf(l2-mx);
        float es = e0 + e1 + e2;
        float w0 = e0/es, w1 = e1/es, w2 = e2/es;
        float mean = (w0 + w1 + w2) * (1.f/3.f);
        float var = ((w0-mean)*(w0-mean) + (w1-mean)*(w1-mean) + (w2-mean)*(w2-mean)) * 0.5f;
        float conflict = sqrtf(var);
        float inv_s = 1.f / (w0 + w1 + w2 + 1e-6f);
        float u0 = w0*inv_s, u1 = w1*inv_s, u2 = w2*inv_s;
        float ent = -(u0*logf(fmaxf(u0,1e-6f)) + u1*logf(fmaxf(u1,1e-6f)) + u2*logf(fmaxf(u2,1e-6f)));
        const float inv = 1.f / (1024.f * 512.f);
        float plast = accv[0] * inv;                 // pred_err mean == last_plasticity
        float nov   = accv[1] * inv;
        float spars = accv[2] * inv;
        float plasticity = 1e-4f * accv[3] * inv;
        float pe2 = accv[4] * (1.f / (1024.f * 512.f * 512.f));
        float na = 0.01f * plast;
        float rvar = pe2 - 2.f*na*plast + na*na;
        sig[0]=plasticity; sig[1]=nov; sig[2]=plast; sig[3]=ent; sig[4]=spars; sig[5]=-plast; sig[6]=rvar;
        ex7[0]=id_emb[t*4+0]; ex7[1]=id_emb[t*4+1]; ex7[2]=id_emb[t*4+2]; ex7[3]=id_emb[t*4+3];
        ex7[4]=nov; ex7[5]=conflict; ex7[6]=plast;
    }
    __syncthreads();
    for (int h = tid; h < 512; h += 256) {
        float aa = gb1[t*512 + h];
#pragma unroll
        for (int j = 0; j < 7; j++) aa += gW1[(t*512 + h)*7 + j] * sig[j];
        gch[h] = fmaxf(aa, 0.f);
        float bb = rb1[h];
#pragma unroll
        for (int e = 0; e < 7; e++) bb += ex7[e] * rW1[(size_t)h * 519 + 512 + e];
        bias_rh[t*512 + h] = bb;
    }
    __syncthreads();
    float p0 = 0.f, p1 = 0.f;
    for (int h = tid; h < 512; h += 256) {
        p0 += gW2[(t*2 + 0)*512 + h] * gch[h];
        p1 += gW2[(t*2 + 1)*512 + h] * gch[h];
    }
    red[tid] = p0; __syncthreads();
    for (int s = 128; s > 0; s >>= 1) { if (tid < s) red[tid] += red[tid + s]; __syncthreads(); }
    if (tid == 0) outDec[t*2 + 0] = red[0] + gb2[t*2 + 0];
    __syncthreads();
    red[tid] = p1; __syncthreads();
    for (int s = 128; s > 0; s >>= 1) { if (tid < s) red[tid] += red[tid + s]; __syncthreads(); }
    if (tid == 0) outDec[t*2 + 1] = red[0] + gb2[t*2 + 1];
}

// ---------------- logits = rh @ rW2^T + rb2 (one wave per row) ----------------
__global__ __launch_bounds__(256) void logits_kernel(
    const u16* __restrict__ rhb, const float* __restrict__ rW2,
    const float* __restrict__ rb2, float* __restrict__ outLg)
{
    __shared__ float T2[512 * 13];
    __shared__ float rb2s[16];
    const int tid = threadIdx.x;
    for (int i = tid; i < 6656; i += 256) {
        int o = i >> 9, j = i & 511;
        T2[j * 13 + o] = rW2[i];    // transposed+13-pitch: conflict-free reads
    }
    if (tid < 13) rb2s[tid] = rb2[tid];
    __syncthreads();
    const int l = tid & 63, wv = tid >> 6;
    const size_t b = (size_t)blockIdx.x * 4 + wv;
    const u16* rrow = rhb + b * 512;
    float rv[8];
#pragma unroll
    for (int jj = 0; jj < 8; jj++) rv[jj] = bf2f(rrow[l + 64 * jj]);
    float p[13];
#pragma unroll
    for (int o = 0; o < 13; o++) p[o] = 0.f;
#pragma unroll
    for (int jj = 0; jj < 8; jj++) {
        const float* tp = T2 + (l + 64 * jj) * 13;
#pragma unroll
        for (int o = 0; o < 13; o++) p[o] += rv[jj] * tp[o];
    }
#pragma unroll
    for (int o = 0; o < 13; o++) {
#pragma unroll
        for (int off = 32; off > 0; off >>= 1) p[o] += __shfl_xor(p[o], off);
    }
    if (l == 0) {
        float* orow = outLg + b * 13;
#pragma unroll
        for (int o = 0; o < 13; o++) orow[o] = p[o] + rb2s[o];
    }
}

extern "C" void kernel_launch(void* const* d_in, const int* in_sizes, int n_in,
                              void* d_out, int out_size, void* d_ws, size_t ws_size,
                              hipStream_t stream)
{
    const float* x         = (const float*)d_in[0];
    const float* Wp        = (const float*)d_in[1];
    const float* bp        = (const float*)d_in[2];
    const float* opW1      = (const float*)d_in[3];
    const float* opb1      = (const float*)d_in[4];
    const float* opW2      = (const float*)d_in[5];
    const float* opb2      = (const float*)d_in[6];
    const float* op_logits = (const float*)d_in[7];
    const float* id_emb    = (const float*)d_in[8];
    const float* rW1       = (const float*)d_in[9];
    const float* rb1       = (const float*)d_in[10];
    const float* rW2       = (const float*)d_in[11];
    const float* rb2       = (const float*)d_in[12];
    const float* gW1       = (const float*)d_in[13];
    const float* gb1       = (const float*)d_in[14];
    const float* gW2       = (const float*)d_in[15];
    const float* gb2       = (const float*)d_in[16];
    const float* phW       = (const float*)d_in[17];
    const float* phb       = (const float*)d_in[18];
    const float* noise     = (const float*)d_in[19];

    char* ws = (char*)d_ws;
    float* wbuf    = (float*)(ws + WS_W);
    float* bias_rh = (float*)(ws + WS_BIASRH);
    u16* wpb  = (u16*)(ws + WS_WPB);
    u16* phwb = (u16*)(ws + WS_PHWB);
    u16* rw1b = (u16*)(ws + WS_RW1B);
    u16* w1b  = (u16*)(ws + WS_W1B);
    u16* w2b  = (u16*)(ws + WS_W2B);
    u16* xpb  = (u16*)(ws + WS_XPB);
    u16* h1b  = (u16*)(ws + WS_H1B);
    u16* xbf  = (u16*)(ws + WS_XBF);
    u16* outb = (u16*)(ws + WS_OUTB);
    u16* rhb  = (u16*)(ws + WS_RHB);
    float* partials = (float*)(ws + WS_W1B);   // aliases w1b, dead after kgemm_h1

    float* outF    = (float*)d_out;
    float* outLg   = outF + OUT_LG;
    float* outPred = outF + OUT_PRED;
    float* outDec  = outF + OUT_DEC;

    cvt6<<<32000, 256, 0, stream>>>(x, xbf, opW1, w1b, opW2, w2b, Wp, wpb,
                                    phW, phwb, rW1, rw1b, op_logits, wbuf);
    kgemm_xp  <<<dim3(4, 192),    256, 0, stream>>>(xbf, wpb, bp, xpb);
    kgemm_h1  <<<dim3(4, 8, 36),  256, 0, stream>>>(xpb, w1b, opb1, h1b);
    kgemm_out <<<dim3(4, 16, 12), 256, 0, stream>>>(h1b, w2b, opb2, wbuf, outF, outb);
    rowred    <<<256,             256, 0, stream>>>(outF, xpb, noise, partials);
    sig_kernel<<<12,              256, 0, stream>>>(op_logits, id_emb, rW1, rb1, gW1, gb1,
                                                    gW2, gb2, partials, bias_rh, outDec);
    kgemm_predrh<<<dim3(12, 96),  256, 0, stream>>>(outb, phwb, phb, rw1b, bias_rh,
                                                    outPred, rhb);
    logits_kernel<<<3072,         256, 0, stream>>>(rhb, rW2, rb2, outLg);
}